// Round 12
// baseline (3630.036 us; speedup 1.0000x reference)
//
#include <hip/hip_runtime.h>
#include <math.h>

// EQGAT edge GNN — round 11/12: k_h replaced by MFMA kernel over layer-invariant
// sorted edge-feature matrix efmat[NE][96] (bf16 hi/lo), with LDS-transposed
// coalesced h stores. Everything else as round 10 (validated).

constexpr int NN  = 10000;   // nodes
constexpr int NE  = 160000;  // edges
constexpr int SD  = 256;     // SDIM
constexpr int VD  = 128;     // VDIM
constexpr int DIN_ = 600;

typedef __attribute__((ext_vector_type(8))) short short8;
typedef __attribute__((ext_vector_type(4))) float f32x4;

static __device__ __forceinline__ float silu_f(float x) {
  return x / (1.0f + expf(-x));
}
static __device__ __forceinline__ ushort f2bf(float x) {
  unsigned u = __float_as_uint(x);
  unsigned r = (u + 0x7FFFu + ((u >> 16) & 1u)) >> 16;
  return (ushort)r;
}
static __device__ __forceinline__ float bf2f(ushort h) {
  return __uint_as_float(((unsigned)h) << 16);
}

// ---------------- setup: in-degree ----------------
__global__ __launch_bounds__(256) void k_setup(
    const int* __restrict__ tgt, float* __restrict__ cnt)
{
  int e = blockIdx.x * 256 + threadIdx.x;
  if (e >= NE) return;
  atomicAdd(&cnt[tgt[e]], 1.0f);
}

__global__ __launch_bounds__(256) void k_invcnt(
    const float* __restrict__ cnt, float* __restrict__ icnt)
{
  int n = blockIdx.x * 256 + threadIdx.x;
  if (n < NN) icnt[n] = 1.0f / fmaxf(cnt[n], 1.0f);
}

// ---------------- exclusive scan of cnt -> rowstart (single block) ----------------
__global__ __launch_bounds__(256) void k_scan(
    const float* __restrict__ cnt, int* __restrict__ rowstart)
{
  __shared__ float buf[256];
  __shared__ float carry_s;
  int tid = threadIdx.x;
  if (tid == 0) carry_s = 0.0f;
  __syncthreads();
  for (int base = 0; base < NN; base += 256) {
    int i = base + tid;
    float c = (i < NN) ? cnt[i] : 0.0f;
    buf[tid] = c;
    __syncthreads();
    for (int off = 1; off < 256; off <<= 1) {
      float v = (tid >= off) ? buf[tid - off] : 0.0f;
      __syncthreads();
      buf[tid] += v;
      __syncthreads();
    }
    float incl = buf[tid];
    float carry = carry_s;
    if (i < NN) rowstart[i] = (int)(carry + incl - c);
    __syncthreads();
    if (tid == 255) carry_s = carry + buf[255];
    __syncthreads();
  }
  if (tid == 0) rowstart[NN] = NE;
}

// ---------------- place edges into sorted-by-target order ----------------
__global__ __launch_bounds__(256) void k_place(
    const int* __restrict__ src, const int* __restrict__ tgt,
    const float* __restrict__ rnorm,
    const int* __restrict__ rowstart, int* __restrict__ fill,
    int* __restrict__ eperm, int* __restrict__ src_s, int* __restrict__ tgt_s,
    float* __restrict__ rn_s)
{
  int e = blockIdx.x * 256 + threadIdx.x;
  if (e >= NE) return;
  int t = tgt[e];
  int pos = rowstart[t] + atomicAdd(&fill[t], 1);
  eperm[pos] = e;
  src_s[pos] = src[e];
  tgt_s[pos] = t;
  rn_s[pos * 4 + 0] = rnorm[(size_t)e * 3 + 0];
  rn_s[pos * 4 + 1] = rnorm[(size_t)e * 3 + 1];
  rn_s[pos * 4 + 2] = rnorm[(size_t)e * 3 + 2];
  rn_s[pos * 4 + 3] = 0.0f;
}

// ---------------- efmat: sorted edge features [p][96] bf16 hi/lo ----------------
// 32 edges/block, 8 threads/edge, 12 features/thread.
__global__ __launch_bounds__(256) void k_efmat(
    const float* __restrict__ edge_d, const float* __restrict__ edge_a,
    const float* __restrict__ edge_e, const float* __restrict__ edge_ohe,
    const float* __restrict__ edge_g, const int* __restrict__ eperm,
    ushort* __restrict__ efm_hi, ushort* __restrict__ efm_lo)
{
  int tid = threadIdx.x;
  int el = tid >> 3, jt = tid & 7;
  int p = blockIdx.x * 32 + el;
  int e = eperm[p];
  float d = edge_d[e];
  float env = 0.0f;
  if (d < 5.0f) env = 0.5f * cosf(d * 0.628318530717958648f) + 0.5f; // pi/5
  #pragma unroll
  for (int jj = 0; jj < 12; ++jj) {
    int j = jt * 12 + jj;
    float val;
    if (j < 20) {
      float x = d - (5.0f / 19.0f) * (float)j;
      val = env * expf(-8.0f * x * x);
    }
    else if (j == 20) val = edge_a[e];
    else if (j < 53)  val = edge_e[(size_t)e * 32 + (j - 21)];
    else if (j < 56)  val = edge_ohe[(size_t)e * 3 + (j - 53)];
    else if (j < 88)  val = edge_g[(size_t)e * 32 + (j - 56)];
    else              val = 0.0f;
    ushort hb = f2bf(val);
    efm_hi[(size_t)p * 96 + j] = hb;
    efm_lo[(size_t)p * 96 + j] = f2bf(val - bf2f(hb));
  }
}

// ---------------- split We1 rows 512..599 -> w1t[n][96] bf16 hi/lo ----------------
__global__ __launch_bounds__(96) void k_w1split(
    const float* __restrict__ W1c,   // [88][256]
    ushort* __restrict__ w1t_hi, ushort* __restrict__ w1t_lo)
{
  int n = blockIdx.x, k = threadIdx.x;   // 256 x 96
  float x = (k < 88) ? W1c[(size_t)k * SD + n] : 0.0f;
  ushort hb = f2bf(x);
  w1t_hi[n * 96 + k] = hb;
  w1t_lo[n * 96 + k] = f2bf(x - bf2f(hb));
}

// ---------------- split-transpose We2 cols 256..511 -> Wg_hi/lo [n][k] bf16 ----------------
__global__ __launch_bounds__(256) void k_w2bf(
    const float* __restrict__ W2,       // [256][512]
    ushort* __restrict__ wg_hi, ushort* __restrict__ wg_lo)
{
  int n = blockIdx.x, k = threadIdx.x;  // 256 x 256
  float x = W2[(size_t)k * 512 + 256 + n];
  ushort hb = f2bf(x);
  wg_hi[n * 256 + k] = hb;
  wg_lo[n * 256 + k] = f2bf(x - bf2f(hb));
}

// ---------------- generic split-transpose W[K][ldw] col n -> wt[nbase+n][K] ----------------
__global__ __launch_bounds__(256) void k_wsplit(
    const float* __restrict__ W, int ldw, int K, int nbase,
    ushort* __restrict__ whi, ushort* __restrict__ wlo)
{
  int n = blockIdx.x;
  for (int k = threadIdx.x; k < K; k += 256) {
    float x = W[(size_t)k * ldw + n];
    ushort hb = f2bf(x);
    whi[(size_t)(nbase + n) * K + k] = hb;
    wlo[(size_t)(nbase + n) * K + k] = f2bf(x - bf2f(hb));
  }
}

// ---------------- LayerNorm(s) + vnorm(v), with optional copies ----------------
__global__ __launch_bounds__(256) void k_ln_vnorm(
    const float* __restrict__ s, const float* __restrict__ v,
    const float* __restrict__ gamma, const float* __restrict__ beta,
    float* __restrict__ s_ln, float* __restrict__ s_copy,
    float* __restrict__ v_n, float* __restrict__ v_copy)
{
  int n = blockIdx.x, t = threadIdx.x;
  __shared__ float red[8];
  float x = s[n * SD + t];
  float ss = x, sq = x * x;
  #pragma unroll
  for (int o = 32; o > 0; o >>= 1) { ss += __shfl_down(ss, o); sq += __shfl_down(sq, o); }
  int wid = t >> 6;
  if ((t & 63) == 0) { red[wid * 2] = ss; red[wid * 2 + 1] = sq; }
  __syncthreads();
  if (t == 0) {
    float S = red[0] + red[2] + red[4] + red[6];
    float Q = red[1] + red[3] + red[5] + red[7];
    float mu = S * (1.0f / SD);
    float var = Q * (1.0f / SD) - mu * mu;
    red[0] = mu; red[1] = rsqrtf(var + 1e-6f);
  }
  __syncthreads();
  float mu = red[0], rstd = red[1];
  float y = (x - mu) * rstd * gamma[t] + beta[t];
  s_ln[n * SD + t] = y;
  if (s_copy) s_copy[n * SD + t] = y;
  __syncthreads();
  float v0 = v[n * 384 + t];
  float v1 = (t < 128) ? v[n * 384 + 256 + t] : 0.0f;
  float q = v0 * v0 + v1 * v1;
  #pragma unroll
  for (int o = 32; o > 0; o >>= 1) q += __shfl_down(q, o);
  if ((t & 63) == 0) red[wid] = q;
  __syncthreads();
  if (t == 0) red[4] = rsqrtf((red[0] + red[1] + red[2] + red[3]) * (1.0f / VD) + 1e-6f);
  __syncthreads();
  float rf = red[4];
  float w0 = v0 * rf;
  v_n[n * 384 + t] = w0;
  if (v_copy) v_copy[n * 384 + t] = w0;
  if (t < 128) {
    float w1 = v1 * rf;
    v_n[n * 384 + 256 + t] = w1;
    if (v_copy) v_copy[n * 384 + 256 + t] = w1;
  }
}

// ---------------- generic MFMA GEMM: C[M,N] = op(A[M,K]fp32 @ wt[n][k]) ----------------
template<int DO_SILU, int SNEXT>
__global__ __launch_bounds__(256) void k_gemm_mf(
    const float* __restrict__ A, int lda,
    const ushort* __restrict__ wt_hi, const ushort* __restrict__ wt_lo,
    const float* __restrict__ bias,
    const float* __restrict__ cntf, const float* __restrict__ icnt,
    float* __restrict__ C, int ldc, int M, int K)
{
  __shared__ __align__(16) ushort Ah[64 * 40];
  __shared__ __align__(16) ushort Al[64 * 40];
  __shared__ __align__(16) ushort Bh[64 * 40];
  __shared__ __align__(16) ushort Bl[64 * 40];
  int n0 = blockIdx.x * 64;
  int m0 = blockIdx.y * 64;
  int tid = threadIdx.x;
  int srow = tid >> 2, sk8 = (tid & 3) * 8;
  int lane = tid & 63, wv = tid >> 6;
  int lg = lane >> 4, lm = lane & 15;
  f32x4 acc[4] = {};
  for (int k0 = 0; k0 < K; k0 += 32) {
    __syncthreads();
    {
      float4 a0 = make_float4(0.f, 0.f, 0.f, 0.f), a1 = a0;
      if (m0 + srow < M) {
        const float4* ap = (const float4*)&A[(size_t)(m0 + srow) * lda + k0 + sk8];
        a0 = ap[0]; a1 = ap[1];
      }
      ushort hi[8], lo[8];
      float af[8] = {a0.x, a0.y, a0.z, a0.w, a1.x, a1.y, a1.z, a1.w};
      #pragma unroll
      for (int j = 0; j < 8; ++j) {
        hi[j] = f2bf(af[j]);
        lo[j] = f2bf(af[j] - bf2f(hi[j]));
      }
      *(uint4*)&Ah[srow * 40 + sk8] = *(const uint4*)hi;
      *(uint4*)&Al[srow * 40 + sk8] = *(const uint4*)lo;
    }
    {
      *(uint4*)&Bh[srow * 40 + sk8] = *(const uint4*)&wt_hi[(size_t)(n0 + srow) * K + k0 + sk8];
      *(uint4*)&Bl[srow * 40 + sk8] = *(const uint4*)&wt_lo[(size_t)(n0 + srow) * K + k0 + sk8];
    }
    __syncthreads();
    short8 ah = *(const short8*)&Ah[(16 * wv + lm) * 40 + 8 * lg];
    short8 al = *(const short8*)&Al[(16 * wv + lm) * 40 + 8 * lg];
    #pragma unroll
    for (int cf = 0; cf < 4; ++cf) {
      short8 bh = *(const short8*)&Bh[(16 * cf + lm) * 40 + 8 * lg];
      short8 bl = *(const short8*)&Bl[(16 * cf + lm) * 40 + 8 * lg];
      acc[cf] = __builtin_amdgcn_mfma_f32_16x16x32_bf16(ah, bh, acc[cf], 0, 0, 0);
      acc[cf] = __builtin_amdgcn_mfma_f32_16x16x32_bf16(ah, bl, acc[cf], 0, 0, 0);
      acc[cf] = __builtin_amdgcn_mfma_f32_16x16x32_bf16(al, bh, acc[cf], 0, 0, 0);
    }
  }
  #pragma unroll
  for (int cf = 0; cf < 4; ++cf) {
    int col = n0 + 16 * cf + lm;
    float b = bias ? bias[col] : 0.0f;
    #pragma unroll
    for (int r = 0; r < 4; ++r) {
      int row = m0 + 16 * wv + 4 * lg + r;
      if (row >= M) continue;
      if (SNEXT) {
        C[(size_t)row * ldc + col] += (acc[cf][r] + cntf[row] * b) * icnt[row];
      } else {
        float val = acc[cf][r] + b;
        if (DO_SILU) val = silu_f(val);
        C[(size_t)row * ldc + col] = val;
      }
    }
  }
}

// ---------------- h = silu(efmat @ w1t + pre1[src] + pre2[tgt] + be1) via MFMA ----------------
// grid ce/64; 4 waves; wave wv owns rows [16wv,16wv+16). K=96 (3 k-steps).
// B tiles looped over 4 col-tiles; h stored via LDS transpose (coalesced).
__global__ __launch_bounds__(256) void k_hmf(
    const ushort* __restrict__ efm_hi, const ushort* __restrict__ efm_lo,
    const ushort* __restrict__ w1t_hi, const ushort* __restrict__ w1t_lo,
    const float* __restrict__ pre12,
    const int* __restrict__ src_s, const int* __restrict__ tgt_s,
    const float* __restrict__ be1,
    int e0,
    ushort* __restrict__ h_hi, ushort* __restrict__ h_lo)
{
  __shared__ __align__(16) ushort Ah[64 * 104];
  __shared__ __align__(16) ushort Al[64 * 104];
  __shared__ __align__(16) ushort Bh[64 * 104];   // reused as Hh [64][72]
  __shared__ __align__(16) ushort Bl[64 * 104];   // reused as Hl
  int lb0 = blockIdx.x * 64;       // chunk-local
  int ge0 = e0 + lb0;              // global sorted pos
  int tid = threadIdx.x;
  int lane = tid & 63, wv = tid >> 6;
  int lg = lane >> 4, lm = lane & 15;
  // stage A once: 64 rows x 96 ushorts = 768 uint4 per array
  #pragma unroll
  for (int i = 0; i < 3; ++i) {
    int task = tid + 256 * i;
    int row = task / 12, sl = task - row * 12;
    *(uint4*)&Ah[row * 104 + sl * 8] = *(const uint4*)&efm_hi[(size_t)(ge0 + row) * 96 + sl * 8];
    *(uint4*)&Al[row * 104 + sl * 8] = *(const uint4*)&efm_lo[(size_t)(ge0 + row) * 96 + sl * 8];
  }
  int sA[4], tA[4];
  #pragma unroll
  for (int rr = 0; rr < 4; ++rr) {
    int p = ge0 + 16 * wv + 4 * lg + rr;
    sA[rr] = src_s[p];
    tA[rr] = tgt_s[p];
  }
  for (int nt = 0; nt < 4; ++nt) {
    __syncthreads();
    #pragma unroll
    for (int i = 0; i < 3; ++i) {
      int task = tid + 256 * i;
      int row = task / 12, sl = task - row * 12;
      *(uint4*)&Bh[row * 104 + sl * 8] = *(const uint4*)&w1t_hi[(size_t)(64 * nt + row) * 96 + sl * 8];
      *(uint4*)&Bl[row * 104 + sl * 8] = *(const uint4*)&w1t_lo[(size_t)(64 * nt + row) * 96 + sl * 8];
    }
    __syncthreads();
    f32x4 acc[4] = {};
    #pragma unroll
    for (int ks = 0; ks < 3; ++ks) {
      short8 ah = *(const short8*)&Ah[(16 * wv + lm) * 104 + 32 * ks + 8 * lg];
      short8 al = *(const short8*)&Al[(16 * wv + lm) * 104 + 32 * ks + 8 * lg];
      #pragma unroll
      for (int nf = 0; nf < 4; ++nf) {
        short8 bh = *(const short8*)&Bh[(16 * nf + lm) * 104 + 32 * ks + 8 * lg];
        short8 bl = *(const short8*)&Bl[(16 * nf + lm) * 104 + 32 * ks + 8 * lg];
        acc[nf] = __builtin_amdgcn_mfma_f32_16x16x32_bf16(ah, bh, acc[nf], 0, 0, 0);
        acc[nf] = __builtin_amdgcn_mfma_f32_16x16x32_bf16(ah, bl, acc[nf], 0, 0, 0);
        acc[nf] = __builtin_amdgcn_mfma_f32_16x16x32_bf16(al, bh, acc[nf], 0, 0, 0);
      }
    }
    // epilogue -> registers
    ushort hh[4][4], hl[4][4];
    #pragma unroll
    for (int nf = 0; nf < 4; ++nf) {
      int col = 64 * nt + 16 * nf + lm;
      float b = be1[col];
      #pragma unroll
      for (int rr = 0; rr < 4; ++rr) {
        float x = acc[nf][rr] + pre12[(size_t)sA[rr] * 512 + col]
                + pre12[(size_t)tA[rr] * 512 + 256 + col] + b;
        float s = silu_f(x);
        ushort hb = f2bf(s);
        hh[nf][rr] = hb;
        hl[nf][rr] = f2bf(s - bf2f(hb));
      }
    }
    __syncthreads();   // all B reads complete before overlay write
    #pragma unroll
    for (int nf = 0; nf < 4; ++nf) {
      #pragma unroll
      for (int rr = 0; rr < 4; ++rr) {
        int row = 16 * wv + 4 * lg + rr;
        Bh[row * 72 + 16 * nf + lm] = hh[nf][rr];
        Bl[row * 72 + 16 * nf + lm] = hl[nf][rr];
      }
    }
    __syncthreads();
    // coalesced store: 64 rows x 8 uint4 per array
    #pragma unroll
    for (int i = 0; i < 2; ++i) {
      int task = tid + 256 * i;
      int row = task >> 3, sl = task & 7;
      *(uint4*)&h_hi[(size_t)(lb0 + row) * 256 + 64 * nt + sl * 8] =
          *(const uint4*)&Bh[row * 72 + sl * 8];
      *(uint4*)&h_lo[(size_t)(lb0 + row) * 256 + 64 * nt + sl * 8] =
          *(const uint4*)&Bl[row * 72 + sl * 8];
    }
  }
}

// ---------------- g = h @ Wg + bias via split-bf16 MFMA, BN=256 ----------------
__global__ __launch_bounds__(256) void k_gmfma(
    const ushort* __restrict__ h_hi, const ushort* __restrict__ h_lo,
    const ushort* __restrict__ wg_hi, const ushort* __restrict__ wg_lo,
    const float* __restrict__ bias,   // 256 entries (be2[256:512])
    float* __restrict__ g)
{
  __shared__ __align__(16) ushort Ah[64 * 40];
  __shared__ __align__(16) ushort Al[64 * 40];
  __shared__ __align__(16) ushort Bh[256 * 40];
  __shared__ __align__(16) ushort Bl[256 * 40];
  int m0 = blockIdx.x * 64;
  int tid = threadIdx.x;
  int srow = tid >> 2, sk8 = (tid & 3) * 8;
  int lane = tid & 63, wv = tid >> 6;
  int lg = lane >> 4, lm = lane & 15;
  f32x4 acc[4][4] = {};
  for (int k0 = 0; k0 < 256; k0 += 32) {
    __syncthreads();
    *(uint4*)&Ah[srow * 40 + sk8] = *(const uint4*)&h_hi[(size_t)(m0 + srow) * 256 + k0 + sk8];
    *(uint4*)&Al[srow * 40 + sk8] = *(const uint4*)&h_lo[(size_t)(m0 + srow) * 256 + k0 + sk8];
    #pragma unroll
    for (int i = 0; i < 4; ++i) {
      int task = tid + 256 * i;
      int brow = task >> 2, c8 = (task & 3) * 8;
      *(uint4*)&Bh[brow * 40 + c8] = *(const uint4*)&wg_hi[(size_t)brow * 256 + k0 + c8];
      *(uint4*)&Bl[brow * 40 + c8] = *(const uint4*)&wg_lo[(size_t)brow * 256 + k0 + c8];
    }
    __syncthreads();
    short8 ah[4], al[4];
    #pragma unroll
    for (int mf = 0; mf < 4; ++mf) {
      ah[mf] = *(const short8*)&Ah[(16 * mf + lm) * 40 + 8 * lg];
      al[mf] = *(const short8*)&Al[(16 * mf + lm) * 40 + 8 * lg];
    }
    #pragma unroll
    for (int nf = 0; nf < 4; ++nf) {
      short8 bh = *(const short8*)&Bh[(64 * wv + 16 * nf + lm) * 40 + 8 * lg];
      short8 bl = *(const short8*)&Bl[(64 * wv + 16 * nf + lm) * 40 + 8 * lg];
      #pragma unroll
      for (int mf = 0; mf < 4; ++mf) {
        acc[mf][nf] = __builtin_amdgcn_mfma_f32_16x16x32_bf16(ah[mf], bh, acc[mf][nf], 0, 0, 0);
        acc[mf][nf] = __builtin_amdgcn_mfma_f32_16x16x32_bf16(ah[mf], bl, acc[mf][nf], 0, 0, 0);
        acc[mf][nf] = __builtin_amdgcn_mfma_f32_16x16x32_bf16(al[mf], bh, acc[mf][nf], 0, 0, 0);
      }
    }
  }
  #pragma unroll
  for (int nf = 0; nf < 4; ++nf) {
    int col = 64 * wv + 16 * nf + lm;
    float b = bias[col];
    #pragma unroll
    for (int mf = 0; mf < 4; ++mf) {
      #pragma unroll
      for (int r = 0; r < 4; ++r) {
        int row = m0 + 16 * mf + 4 * lg + r;
        g[(size_t)row * 256 + col] = acc[mf][nf][r] + b;
      }
    }
  }
}

// ---------------- per-node contiguous gather (no atomics) ----------------
__global__ __launch_bounds__(256) void k_gather(
    const ushort* __restrict__ h_hi, const ushort* __restrict__ h_lo,
    const float* __restrict__ g,
    const int* __restrict__ rowstart,
    const int* __restrict__ src_s,
    const float* __restrict__ rn_s,
    const float* __restrict__ v_n,
    const float* __restrict__ icnt,
    int e0, int ce,
    float* __restrict__ hsum, float* __restrict__ v_next)
{
  int t = blockIdx.x;
  int lo = rowstart[t], hi = rowstart[t + 1];
  if (lo < e0) lo = e0;
  int e1 = e0 + ce;
  if (hi > e1) hi = e1;
  if (lo >= hi) return;
  int tid = threadIdx.x;
  int k = tid & 127, half = tid >> 7;
  float hacc = 0.0f, a0 = 0.0f, a1 = 0.0f, a2 = 0.0f;
  for (int p = lo; p < hi; ++p) {
    int lp = p - e0;
    hacc += bf2f(h_hi[(size_t)lp * SD + tid]) + bf2f(h_lo[(size_t)lp * SD + tid]);
    float gr = g[(size_t)lp * SD + k];
    float gv = g[(size_t)lp * SD + 128 + k];
    int sn = src_s[p];
    const float* vs = &v_n[(size_t)sn * 384];
    if (half == 0) {
      float r0 = rn_s[(size_t)p * 4 + 0];
      float r2 = rn_s[(size_t)p * 4 + 2];
      a0 += gr * r0 + gv * vs[k];
      a2 += gr * r2 + gv * vs[256 + k];
    } else {
      float r1 = rn_s[(size_t)p * 4 + 1];
      a1 += gr * r1 + gv * vs[128 + k];
    }
  }
  hsum[(size_t)t * SD + tid] += hacc;
  float ic = icnt[t];
  if (half == 0) {
    v_next[(size_t)t * 384 + k]       += ic * a0;
    v_next[(size_t)t * 384 + 256 + k] += ic * a2;
  } else {
    v_next[(size_t)t * 384 + 128 + k] += ic * a1;
  }
}

// ---------------- nv = sqrt(sum_c vv^2 + eps); xcat = [s | nv] ----------------
__global__ __launch_bounds__(256) void k_nv_xcat(
    const float* __restrict__ vv, const float* __restrict__ s_next,
    float* __restrict__ xcat)
{
  int n = blockIdx.x, t = threadIdx.x;
  xcat[(size_t)n * 384 + t] = s_next[(size_t)n * SD + t];
  if (t < 128) {
    float a = vv[(size_t)(n * 3 + 0) * VD + t];
    float b = vv[(size_t)(n * 3 + 1) * VD + t];
    float c = vv[(size_t)(n * 3 + 2) * VD + t];
    xcat[(size_t)n * 384 + 256 + t] = sqrtf(a * a + b * b + c * c + 1e-6f);
  }
}

// ---------------- s_cur = s_next + u[:, :256]; v_cur = v_next + vv * u[:, None, 256:] ----------------
__global__ __launch_bounds__(256) void k_update(
    const float* __restrict__ s_next, const float* __restrict__ v_next,
    const float* __restrict__ vv, const float* __restrict__ u,
    float* __restrict__ s_cur, float* __restrict__ v_cur)
{
  int i = blockIdx.x * 256 + threadIdx.x;
  const int NVT = NN * 384;
  if (i < NVT) {
    int n = i / 384;
    int k = (i - n * 384) & 127;
    v_cur[i] = v_next[i] + vv[i] * u[(size_t)n * 384 + 256 + k];
  } else {
    int j = i - NVT;
    if (j < NN * SD) {
      int n = j >> 8, c = j & 255;
      s_cur[j] = s_next[j] + u[(size_t)n * 384 + c];
    }
  }
}

// =====================================================================
extern "C" void kernel_launch(void* const* d_in, const int* in_sizes, int n_in,
                              void* d_out, int out_size, void* d_ws, size_t ws_size,
                              hipStream_t stream)
{
  const float* s_in   = (const float*)d_in[0];
  const float* v_in   = (const float*)d_in[1];
  const float* p_in   = (const float*)d_in[2];
  const int*   eidx   = (const int*)d_in[3];
  const float* edge_d = (const float*)d_in[4];
  const float* edge_a = (const float*)d_in[5];
  const float* rnorm  = (const float*)d_in[6];
  const float* edge_e = (const float*)d_in[7];
  const float* edge_o = (const float*)d_in[8];
  const float* edge_g = (const float*)d_in[9];
  const float* gamma  = (const float*)d_in[10];
  const float* beta   = (const float*)d_in[11];
  const float* We1    = (const float*)d_in[12];
  const float* be1    = (const float*)d_in[13];
  const float* We2    = (const float*)d_in[14];
  const float* be2    = (const float*)d_in[15];
  const float* Wvu    = (const float*)d_in[16];
  const float* Wu1    = (const float*)d_in[17];
  const float* bu1    = (const float*)d_in[18];
  const float* Wu2    = (const float*)d_in[19];
  const float* bu2    = (const float*)d_in[20];
  const int* srcA = eidx;
  const int* tgtA = eidx + NE;

  float* w = (float*)d_ws;
  float* s_cur  = w; w += NN * SD;
  float* v_cur  = w; w += NN * 384;
  float* s_ln   = w; w += NN * SD;      // reused later as tbuf
  float* v_nrm  = w; w += NN * 384;     // reused later as ubuf
  float* s_next = w; w += NN * SD;
  float* v_next = w; w += NN * 384;
  float* pre12  = w; w += NN * 512;     // reused later as xcat (N*384)
  float* cnt    = w; w += NN;
  float* icnt   = w; w += NN;
  float* vv     = w; w += NN * 384;
  float* hsum   = w; w += NN * SD;
  ushort* wg_hi = (ushort*)w; w += 32768;   // 256*256 bf16
  ushort* wg_lo = (ushort*)w; w += 32768;
  ushort* wt_hi = (ushort*)w; w += 65536;   // up to 512*256 bf16 (node weights)
  ushort* wt_lo = (ushort*)w; w += 65536;
  ushort* w1t_hi = (ushort*)w; w += 12288;  // 256*96 bf16
  ushort* w1t_lo = (ushort*)w; w += 12288;
  ushort* efm_hi = (ushort*)w; w += (size_t)NE * 48;  // NE*96 ushorts
  ushort* efm_lo = (ushort*)w; w += (size_t)NE * 48;
  int*   rowstart = (int*)w; w += NN + 4;   // padded to keep 16B alignment
  int*   fill     = (int*)w; w += NN;
  int*   eperm    = (int*)w; w += NE;
  int*   src_s    = (int*)w; w += NE;
  int*   tgt_s    = (int*)w; w += NE;
  float* rn_s   = w; w += (size_t)NE * 4;
  float* tbuf = s_ln;
  float* ubuf = v_nrm;
  float* xcat = pre12;

  // chunking: per chunk need chunkE*256 ushort (h_hi) + same (h_lo) + chunkE*256
  // float (g) = chunkE*512 floats total in the remainder
  size_t fixedF = (size_t)(w - (float*)d_ws);
  size_t totalF = ws_size / sizeof(float);
  size_t availF = (totalF > fixedF) ? (totalF - fixedF) : 0;
  long long mc = (long long)(availF / 512) & ~127LL;   // multiple of 128 edges
  if (mc > NE) mc = NE;
  if (mc < 128) mc = 128;
  const int chunkE = (int)mc;
  ushort* h_hi = (ushort*)w;
  ushort* h_lo = h_hi + (size_t)chunkE * SD;
  float*  gbuf = (float*)(h_lo + (size_t)chunkE * SD);

  hipMemsetAsync(cnt, 0, NN * sizeof(float), stream);
  hipMemsetAsync(fill, 0, NN * sizeof(int), stream);
  k_setup<<<(NE + 255) / 256, 256, 0, stream>>>(tgtA, cnt);
  k_scan<<<1, 256, 0, stream>>>(cnt, rowstart);
  k_invcnt<<<(NN + 255) / 256, 256, 0, stream>>>(cnt, icnt);
  k_place<<<(NE + 255) / 256, 256, 0, stream>>>(srcA, tgtA, rnorm, rowstart, fill,
                                                eperm, src_s, tgt_s, rn_s);
  k_efmat<<<NE / 32, 256, 0, stream>>>(edge_d, edge_a, edge_e, edge_o, edge_g,
                                       eperm, efm_hi, efm_lo);

  const int MT = 157;   // ceil(10000/64)
  const float* sp = s_in;
  const float* vp = v_in;
  for (int i = 0; i < 5; ++i) {
    k_ln_vnorm<<<NN, 256, 0, stream>>>(sp, vp, gamma + i * SD, beta + i * SD,
                                       s_ln, s_next, v_nrm, v_next);
    const float* W1 = We1 + (size_t)i * DIN_ * SD;
    const float* W2 = We2 + (size_t)i * SD * 512;
    k_w2bf<<<256, 256, 0, stream>>>(W2, wg_hi, wg_lo);
    k_w1split<<<256, 96, 0, stream>>>(W1 + 512 * SD, w1t_hi, w1t_lo);
    // pre12 = s_ln @ [W1a | W1b]  (combined N=512, K=256) via MFMA
    k_wsplit<<<256, 256, 0, stream>>>(W1, SD, 256, 0, wt_hi, wt_lo);
    k_wsplit<<<256, 256, 0, stream>>>(W1 + 256 * SD, SD, 256, 256, wt_hi, wt_lo);
    k_gemm_mf<0, 0><<<dim3(8, MT), 256, 0, stream>>>(
        s_ln, SD, wt_hi, wt_lo, nullptr, nullptr, nullptr, pre12, 512, NN, 256);
    hipMemsetAsync(hsum, 0, (size_t)NN * SD * sizeof(float), stream);
    for (int e0 = 0; e0 < NE; e0 += chunkE) {
      int ce = NE - e0; if (ce > chunkE) ce = chunkE;
      k_hmf<<<ce / 64, 256, 0, stream>>>(efm_hi, efm_lo, w1t_hi, w1t_lo, pre12,
                                         src_s, tgt_s, be1 + i * SD, e0, h_hi, h_lo);
      k_gmfma<<<ce / 64, 256, 0, stream>>>(h_hi, h_lo, wg_hi, wg_lo,
                                           be2 + i * 512 + 256, gbuf);
      k_gather<<<NN, 256, 0, stream>>>(h_hi, h_lo, gbuf, rowstart, src_s, rn_s,
                                       v_nrm, icnt, e0, ce, hsum, v_next);
    }
    // s_next += (hsum @ We2[:,0:256] + cnt*be2[0:256]) * icnt  via MFMA
    k_wsplit<<<256, 256, 0, stream>>>(W2, 512, 256, 0, wt_hi, wt_lo);
    k_gemm_mf<0, 1><<<dim3(4, MT), 256, 0, stream>>>(
        hsum, SD, wt_hi, wt_lo, be2 + i * 512, cnt, icnt, s_next, SD, NN, 256);
    if (i < 4) {
      k_wsplit<<<128, 256, 0, stream>>>(Wvu + i * VD * VD, VD, VD, 0, wt_hi, wt_lo);
      k_gemm_mf<0, 0><<<dim3(2, 469), 256, 0, stream>>>(
          v_next, VD, wt_hi, wt_lo, nullptr, nullptr, nullptr, vv, VD, 3 * NN, VD);
      k_nv_xcat<<<NN, 256, 0, stream>>>(vv, s_next, xcat);
      k_wsplit<<<256, 256, 0, stream>>>(Wu1 + (size_t)i * 384 * SD, SD, 384, 0, wt_hi, wt_lo);
      k_gemm_mf<1, 0><<<dim3(4, MT), 256, 0, stream>>>(
          xcat, 384, wt_hi, wt_lo, bu1 + i * SD, nullptr, nullptr, tbuf, SD, NN, 384);
      k_wsplit<<<384, 256, 0, stream>>>(Wu2 + (size_t)i * SD * 384, 384, 256, 0, wt_hi, wt_lo);
      k_gemm_mf<0, 0><<<dim3(6, MT), 256, 0, stream>>>(
          tbuf, SD, wt_hi, wt_lo, bu2 + i * 384, nullptr, nullptr, ubuf, 384, NN, 256);
      k_update<<<(NN * 640 + 255) / 256, 256, 0, stream>>>(s_next, v_next, vv, ubuf,
                                                           s_cur, v_cur);
      sp = s_cur; vp = v_cur;
    }
  }
  float* out = (float*)d_out;
  k_ln_vnorm<<<NN, 256, 0, stream>>>(s_next, v_next, gamma + 5 * SD, beta + 5 * SD,
                                     out, nullptr, out + NN * SD, nullptr);
  float* outp = out + (size_t)NN * SD + (size_t)NN * 384;
  hipMemcpyAsync(outp, p_in, NN * 3 * sizeof(float), hipMemcpyDeviceToDevice, stream);
  hipMemcpyAsync(outp + NN * 3, edge_e, (size_t)NE * 32 * sizeof(float),
                 hipMemcpyDeviceToDevice, stream);
}

// Round 13
// 3162.145 us; speedup vs baseline: 1.1480x; 1.1480x over previous
//
#include <hip/hip_runtime.h>
#include <math.h>

// EQGAT edge GNN — round 13: coalesced k_efmat (LDS-staged uint4 writes),
// hsum aliased onto vv, eperm moved to chunk scratch (fixed 190->179 MB,
// chunks 5->4). Everything else as round 12 (validated, absmax 0.015625).

constexpr int NN  = 10000;   // nodes
constexpr int NE  = 160000;  // edges
constexpr int SD  = 256;     // SDIM
constexpr int VD  = 128;     // VDIM
constexpr int DIN_ = 600;

typedef __attribute__((ext_vector_type(8))) short short8;
typedef __attribute__((ext_vector_type(4))) float f32x4;

static __device__ __forceinline__ float silu_f(float x) {
  return x / (1.0f + expf(-x));
}
static __device__ __forceinline__ ushort f2bf(float x) {
  unsigned u = __float_as_uint(x);
  unsigned r = (u + 0x7FFFu + ((u >> 16) & 1u)) >> 16;
  return (ushort)r;
}
static __device__ __forceinline__ float bf2f(ushort h) {
  return __uint_as_float(((unsigned)h) << 16);
}

// ---------------- setup: in-degree ----------------
__global__ __launch_bounds__(256) void k_setup(
    const int* __restrict__ tgt, float* __restrict__ cnt)
{
  int e = blockIdx.x * 256 + threadIdx.x;
  if (e >= NE) return;
  atomicAdd(&cnt[tgt[e]], 1.0f);
}

__global__ __launch_bounds__(256) void k_invcnt(
    const float* __restrict__ cnt, float* __restrict__ icnt)
{
  int n = blockIdx.x * 256 + threadIdx.x;
  if (n < NN) icnt[n] = 1.0f / fmaxf(cnt[n], 1.0f);
}

// ---------------- exclusive scan of cnt -> rowstart (single block) ----------------
__global__ __launch_bounds__(256) void k_scan(
    const float* __restrict__ cnt, int* __restrict__ rowstart)
{
  __shared__ float buf[256];
  __shared__ float carry_s;
  int tid = threadIdx.x;
  if (tid == 0) carry_s = 0.0f;
  __syncthreads();
  for (int base = 0; base < NN; base += 256) {
    int i = base + tid;
    float c = (i < NN) ? cnt[i] : 0.0f;
    buf[tid] = c;
    __syncthreads();
    for (int off = 1; off < 256; off <<= 1) {
      float v = (tid >= off) ? buf[tid - off] : 0.0f;
      __syncthreads();
      buf[tid] += v;
      __syncthreads();
    }
    float incl = buf[tid];
    float carry = carry_s;
    if (i < NN) rowstart[i] = (int)(carry + incl - c);
    __syncthreads();
    if (tid == 255) carry_s = carry + buf[255];
    __syncthreads();
  }
  if (tid == 0) rowstart[NN] = NE;
}

// ---------------- place edges into sorted-by-target order ----------------
__global__ __launch_bounds__(256) void k_place(
    const int* __restrict__ src, const int* __restrict__ tgt,
    const float* __restrict__ rnorm,
    const int* __restrict__ rowstart, int* __restrict__ fill,
    int* __restrict__ eperm, int* __restrict__ src_s, int* __restrict__ tgt_s,
    float* __restrict__ rn_s)
{
  int e = blockIdx.x * 256 + threadIdx.x;
  if (e >= NE) return;
  int t = tgt[e];
  int pos = rowstart[t] + atomicAdd(&fill[t], 1);
  eperm[pos] = e;
  src_s[pos] = src[e];
  tgt_s[pos] = t;
  rn_s[pos * 4 + 0] = rnorm[(size_t)e * 3 + 0];
  rn_s[pos * 4 + 1] = rnorm[(size_t)e * 3 + 1];
  rn_s[pos * 4 + 2] = rnorm[(size_t)e * 3 + 2];
  rn_s[pos * 4 + 3] = 0.0f;
}

// ---------------- efmat: sorted edge features [p][96] bf16 hi/lo ----------------
// 32 edges/block; compute into LDS (8 threads/edge x 12 feats), then
// uint4-coalesced global writes (fix for 7x write amplification, r12 PMC).
__global__ __launch_bounds__(256) void k_efmat(
    const float* __restrict__ edge_d, const float* __restrict__ edge_a,
    const float* __restrict__ edge_e, const float* __restrict__ edge_ohe,
    const float* __restrict__ edge_g, const int* __restrict__ eperm,
    ushort* __restrict__ efm_hi, ushort* __restrict__ efm_lo)
{
  __shared__ __align__(16) ushort sh[32 * 96];
  __shared__ __align__(16) ushort sl_[32 * 96];
  int tid = threadIdx.x;
  int el = tid >> 3, jt = tid & 7;
  int p0 = blockIdx.x * 32;
  int e = eperm[p0 + el];
  float d = edge_d[e];
  float env = 0.0f;
  if (d < 5.0f) env = 0.5f * cosf(d * 0.628318530717958648f) + 0.5f; // pi/5
  #pragma unroll
  for (int jj = 0; jj < 12; ++jj) {
    int j = jt * 12 + jj;
    float val;
    if (j < 20) {
      float x = d - (5.0f / 19.0f) * (float)j;
      val = env * expf(-8.0f * x * x);
    }
    else if (j == 20) val = edge_a[e];
    else if (j < 53)  val = edge_e[(size_t)e * 32 + (j - 21)];
    else if (j < 56)  val = edge_ohe[(size_t)e * 3 + (j - 53)];
    else if (j < 88)  val = edge_g[(size_t)e * 32 + (j - 56)];
    else              val = 0.0f;
    ushort hb = f2bf(val);
    sh[el * 96 + j] = hb;
    sl_[el * 96 + j] = f2bf(val - bf2f(hb));
  }
  __syncthreads();
  #pragma unroll
  for (int i = 0; i < 2; ++i) {
    int task = tid + 256 * i;     // 384 uint4 tasks per array
    if (task < 384) {
      int row = task / 12, s8 = (task - row * 12) * 8;
      *(uint4*)&efm_hi[(size_t)(p0 + row) * 96 + s8] = *(const uint4*)&sh[row * 96 + s8];
      *(uint4*)&efm_lo[(size_t)(p0 + row) * 96 + s8] = *(const uint4*)&sl_[row * 96 + s8];
    }
  }
}

// ---------------- split We1 rows 512..599 -> w1t[n][96] bf16 hi/lo ----------------
__global__ __launch_bounds__(96) void k_w1split(
    const float* __restrict__ W1c,   // [88][256]
    ushort* __restrict__ w1t_hi, ushort* __restrict__ w1t_lo)
{
  int n = blockIdx.x, k = threadIdx.x;   // 256 x 96
  float x = (k < 88) ? W1c[(size_t)k * SD + n] : 0.0f;
  ushort hb = f2bf(x);
  w1t_hi[n * 96 + k] = hb;
  w1t_lo[n * 96 + k] = f2bf(x - bf2f(hb));
}

// ---------------- split-transpose We2 cols 256..511 -> Wg_hi/lo [n][k] bf16 ----------------
__global__ __launch_bounds__(256) void k_w2bf(
    const float* __restrict__ W2,       // [256][512]
    ushort* __restrict__ wg_hi, ushort* __restrict__ wg_lo)
{
  int n = blockIdx.x, k = threadIdx.x;  // 256 x 256
  float x = W2[(size_t)k * 512 + 256 + n];
  ushort hb = f2bf(x);
  wg_hi[n * 256 + k] = hb;
  wg_lo[n * 256 + k] = f2bf(x - bf2f(hb));
}

// ---------------- generic split-transpose W[K][ldw] col n -> wt[nbase+n][K] ----------------
__global__ __launch_bounds__(256) void k_wsplit(
    const float* __restrict__ W, int ldw, int K, int nbase,
    ushort* __restrict__ whi, ushort* __restrict__ wlo)
{
  int n = blockIdx.x;
  for (int k = threadIdx.x; k < K; k += 256) {
    float x = W[(size_t)k * ldw + n];
    ushort hb = f2bf(x);
    whi[(size_t)(nbase + n) * K + k] = hb;
    wlo[(size_t)(nbase + n) * K + k] = f2bf(x - bf2f(hb));
  }
}

// ---------------- LayerNorm(s) + vnorm(v), with optional copies ----------------
__global__ __launch_bounds__(256) void k_ln_vnorm(
    const float* __restrict__ s, const float* __restrict__ v,
    const float* __restrict__ gamma, const float* __restrict__ beta,
    float* __restrict__ s_ln, float* __restrict__ s_copy,
    float* __restrict__ v_n, float* __restrict__ v_copy)
{
  int n = blockIdx.x, t = threadIdx.x;
  __shared__ float red[8];
  float x = s[n * SD + t];
  float ss = x, sq = x * x;
  #pragma unroll
  for (int o = 32; o > 0; o >>= 1) { ss += __shfl_down(ss, o); sq += __shfl_down(sq, o); }
  int wid = t >> 6;
  if ((t & 63) == 0) { red[wid * 2] = ss; red[wid * 2 + 1] = sq; }
  __syncthreads();
  if (t == 0) {
    float S = red[0] + red[2] + red[4] + red[6];
    float Q = red[1] + red[3] + red[5] + red[7];
    float mu = S * (1.0f / SD);
    float var = Q * (1.0f / SD) - mu * mu;
    red[0] = mu; red[1] = rsqrtf(var + 1e-6f);
  }
  __syncthreads();
  float mu = red[0], rstd = red[1];
  float y = (x - mu) * rstd * gamma[t] + beta[t];
  s_ln[n * SD + t] = y;
  if (s_copy) s_copy[n * SD + t] = y;
  __syncthreads();
  float v0 = v[n * 384 + t];
  float v1 = (t < 128) ? v[n * 384 + 256 + t] : 0.0f;
  float q = v0 * v0 + v1 * v1;
  #pragma unroll
  for (int o = 32; o > 0; o >>= 1) q += __shfl_down(q, o);
  if ((t & 63) == 0) red[wid] = q;
  __syncthreads();
  if (t == 0) red[4] = rsqrtf((red[0] + red[1] + red[2] + red[3]) * (1.0f / VD) + 1e-6f);
  __syncthreads();
  float rf = red[4];
  float w0 = v0 * rf;
  v_n[n * 384 + t] = w0;
  if (v_copy) v_copy[n * 384 + t] = w0;
  if (t < 128) {
    float w1 = v1 * rf;
    v_n[n * 384 + 256 + t] = w1;
    if (v_copy) v_copy[n * 384 + 256 + t] = w1;
  }
}

// ---------------- generic MFMA GEMM: C[M,N] = op(A[M,K]fp32 @ wt[n][k]) ----------------
template<int DO_SILU, int SNEXT>
__global__ __launch_bounds__(256) void k_gemm_mf(
    const float* __restrict__ A, int lda,
    const ushort* __restrict__ wt_hi, const ushort* __restrict__ wt_lo,
    const float* __restrict__ bias,
    const float* __restrict__ cntf, const float* __restrict__ icnt,
    float* __restrict__ C, int ldc, int M, int K)
{
  __shared__ __align__(16) ushort Ah[64 * 40];
  __shared__ __align__(16) ushort Al[64 * 40];
  __shared__ __align__(16) ushort Bh[64 * 40];
  __shared__ __align__(16) ushort Bl[64 * 40];
  int n0 = blockIdx.x * 64;
  int m0 = blockIdx.y * 64;
  int tid = threadIdx.x;
  int srow = tid >> 2, sk8 = (tid & 3) * 8;
  int lane = tid & 63, wv = tid >> 6;
  int lg = lane >> 4, lm = lane & 15;
  f32x4 acc[4] = {};
  for (int k0 = 0; k0 < K; k0 += 32) {
    __syncthreads();
    {
      float4 a0 = make_float4(0.f, 0.f, 0.f, 0.f), a1 = a0;
      if (m0 + srow < M) {
        const float4* ap = (const float4*)&A[(size_t)(m0 + srow) * lda + k0 + sk8];
        a0 = ap[0]; a1 = ap[1];
      }
      ushort hi[8], lo[8];
      float af[8] = {a0.x, a0.y, a0.z, a0.w, a1.x, a1.y, a1.z, a1.w};
      #pragma unroll
      for (int j = 0; j < 8; ++j) {
        hi[j] = f2bf(af[j]);
        lo[j] = f2bf(af[j] - bf2f(hi[j]));
      }
      *(uint4*)&Ah[srow * 40 + sk8] = *(const uint4*)hi;
      *(uint4*)&Al[srow * 40 + sk8] = *(const uint4*)lo;
    }
    {
      *(uint4*)&Bh[srow * 40 + sk8] = *(const uint4*)&wt_hi[(size_t)(n0 + srow) * K + k0 + sk8];
      *(uint4*)&Bl[srow * 40 + sk8] = *(const uint4*)&wt_lo[(size_t)(n0 + srow) * K + k0 + sk8];
    }
    __syncthreads();
    short8 ah = *(const short8*)&Ah[(16 * wv + lm) * 40 + 8 * lg];
    short8 al = *(const short8*)&Al[(16 * wv + lm) * 40 + 8 * lg];
    #pragma unroll
    for (int cf = 0; cf < 4; ++cf) {
      short8 bh = *(const short8*)&Bh[(16 * cf + lm) * 40 + 8 * lg];
      short8 bl = *(const short8*)&Bl[(16 * cf + lm) * 40 + 8 * lg];
      acc[cf] = __builtin_amdgcn_mfma_f32_16x16x32_bf16(ah, bh, acc[cf], 0, 0, 0);
      acc[cf] = __builtin_amdgcn_mfma_f32_16x16x32_bf16(ah, bl, acc[cf], 0, 0, 0);
      acc[cf] = __builtin_amdgcn_mfma_f32_16x16x32_bf16(al, bh, acc[cf], 0, 0, 0);
    }
  }
  #pragma unroll
  for (int cf = 0; cf < 4; ++cf) {
    int col = n0 + 16 * cf + lm;
    float b = bias ? bias[col] : 0.0f;
    #pragma unroll
    for (int r = 0; r < 4; ++r) {
      int row = m0 + 16 * wv + 4 * lg + r;
      if (row >= M) continue;
      if (SNEXT) {
        C[(size_t)row * ldc + col] += (acc[cf][r] + cntf[row] * b) * icnt[row];
      } else {
        float val = acc[cf][r] + b;
        if (DO_SILU) val = silu_f(val);
        C[(size_t)row * ldc + col] = val;
      }
    }
  }
}

// ---------------- h = silu(efmat @ w1t + pre1[src] + pre2[tgt] + be1) via MFMA ----------------
__global__ __launch_bounds__(256) void k_hmf(
    const ushort* __restrict__ efm_hi, const ushort* __restrict__ efm_lo,
    const ushort* __restrict__ w1t_hi, const ushort* __restrict__ w1t_lo,
    const float* __restrict__ pre12,
    const int* __restrict__ src_s, const int* __restrict__ tgt_s,
    const float* __restrict__ be1,
    int e0,
    ushort* __restrict__ h_hi, ushort* __restrict__ h_lo)
{
  __shared__ __align__(16) ushort Ah[64 * 104];
  __shared__ __align__(16) ushort Al[64 * 104];
  __shared__ __align__(16) ushort Bh[64 * 104];   // reused as Hh [64][72]
  __shared__ __align__(16) ushort Bl[64 * 104];   // reused as Hl
  int lb0 = blockIdx.x * 64;       // chunk-local
  int ge0 = e0 + lb0;              // global sorted pos
  int tid = threadIdx.x;
  int lane = tid & 63, wv = tid >> 6;
  int lg = lane >> 4, lm = lane & 15;
  #pragma unroll
  for (int i = 0; i < 3; ++i) {
    int task = tid + 256 * i;
    int row = task / 12, sl = task - row * 12;
    *(uint4*)&Ah[row * 104 + sl * 8] = *(const uint4*)&efm_hi[(size_t)(ge0 + row) * 96 + sl * 8];
    *(uint4*)&Al[row * 104 + sl * 8] = *(const uint4*)&efm_lo[(size_t)(ge0 + row) * 96 + sl * 8];
  }
  int sA[4], tA[4];
  #pragma unroll
  for (int rr = 0; rr < 4; ++rr) {
    int p = ge0 + 16 * wv + 4 * lg + rr;
    sA[rr] = src_s[p];
    tA[rr] = tgt_s[p];
  }
  for (int nt = 0; nt < 4; ++nt) {
    __syncthreads();
    #pragma unroll
    for (int i = 0; i < 3; ++i) {
      int task = tid + 256 * i;
      int row = task / 12, sl = task - row * 12;
      *(uint4*)&Bh[row * 104 + sl * 8] = *(const uint4*)&w1t_hi[(size_t)(64 * nt + row) * 96 + sl * 8];
      *(uint4*)&Bl[row * 104 + sl * 8] = *(const uint4*)&w1t_lo[(size_t)(64 * nt + row) * 96 + sl * 8];
    }
    __syncthreads();
    f32x4 acc[4] = {};
    #pragma unroll
    for (int ks = 0; ks < 3; ++ks) {
      short8 ah = *(const short8*)&Ah[(16 * wv + lm) * 104 + 32 * ks + 8 * lg];
      short8 al = *(const short8*)&Al[(16 * wv + lm) * 104 + 32 * ks + 8 * lg];
      #pragma unroll
      for (int nf = 0; nf < 4; ++nf) {
        short8 bh = *(const short8*)&Bh[(16 * nf + lm) * 104 + 32 * ks + 8 * lg];
        short8 bl = *(const short8*)&Bl[(16 * nf + lm) * 104 + 32 * ks + 8 * lg];
        acc[nf] = __builtin_amdgcn_mfma_f32_16x16x32_bf16(ah, bh, acc[nf], 0, 0, 0);
        acc[nf] = __builtin_amdgcn_mfma_f32_16x16x32_bf16(ah, bl, acc[nf], 0, 0, 0);
        acc[nf] = __builtin_amdgcn_mfma_f32_16x16x32_bf16(al, bh, acc[nf], 0, 0, 0);
      }
    }
    // epilogue -> registers
    ushort hh[4][4], hl[4][4];
    #pragma unroll
    for (int nf = 0; nf < 4; ++nf) {
      int col = 64 * nt + 16 * nf + lm;
      float b = be1[col];
      #pragma unroll
      for (int rr = 0; rr < 4; ++rr) {
        float x = acc[nf][rr] + pre12[(size_t)sA[rr] * 512 + col]
                + pre12[(size_t)tA[rr] * 512 + 256 + col] + b;
        float s = silu_f(x);
        ushort hb = f2bf(s);
        hh[nf][rr] = hb;
        hl[nf][rr] = f2bf(s - bf2f(hb));
      }
    }
    __syncthreads();   // all B reads complete before overlay write
    #pragma unroll
    for (int nf = 0; nf < 4; ++nf) {
      #pragma unroll
      for (int rr = 0; rr < 4; ++rr) {
        int row = 16 * wv + 4 * lg + rr;
        Bh[row * 72 + 16 * nf + lm] = hh[nf][rr];
        Bl[row * 72 + 16 * nf + lm] = hl[nf][rr];
      }
    }
    __syncthreads();
    #pragma unroll
    for (int i = 0; i < 2; ++i) {
      int task = tid + 256 * i;
      int row = task >> 3, sl = task & 7;
      *(uint4*)&h_hi[(size_t)(lb0 + row) * 256 + 64 * nt + sl * 8] =
          *(const uint4*)&Bh[row * 72 + sl * 8];
      *(uint4*)&h_lo[(size_t)(lb0 + row) * 256 + 64 * nt + sl * 8] =
          *(const uint4*)&Bl[row * 72 + sl * 8];
    }
  }
}

// ---------------- g = h @ Wg + bias via split-bf16 MFMA, BN=256 ----------------
__global__ __launch_bounds__(256) void k_gmfma(
    const ushort* __restrict__ h_hi, const ushort* __restrict__ h_lo,
    const ushort* __restrict__ wg_hi, const ushort* __restrict__ wg_lo,
    const float* __restrict__ bias,   // 256 entries (be2[256:512])
    float* __restrict__ g)
{
  __shared__ __align__(16) ushort Ah[64 * 40];
  __shared__ __align__(16) ushort Al[64 * 40];
  __shared__ __align__(16) ushort Bh[256 * 40];
  __shared__ __align__(16) ushort Bl[256 * 40];
  int m0 = blockIdx.x * 64;
  int tid = threadIdx.x;
  int srow = tid >> 2, sk8 = (tid & 3) * 8;
  int lane = tid & 63, wv = tid >> 6;
  int lg = lane >> 4, lm = lane & 15;
  f32x4 acc[4][4] = {};
  for (int k0 = 0; k0 < 256; k0 += 32) {
    __syncthreads();
    *(uint4*)&Ah[srow * 40 + sk8] = *(const uint4*)&h_hi[(size_t)(m0 + srow) * 256 + k0 + sk8];
    *(uint4*)&Al[srow * 40 + sk8] = *(const uint4*)&h_lo[(size_t)(m0 + srow) * 256 + k0 + sk8];
    #pragma unroll
    for (int i = 0; i < 4; ++i) {
      int task = tid + 256 * i;
      int brow = task >> 2, c8 = (task & 3) * 8;
      *(uint4*)&Bh[brow * 40 + c8] = *(const uint4*)&wg_hi[(size_t)brow * 256 + k0 + c8];
      *(uint4*)&Bl[brow * 40 + c8] = *(const uint4*)&wg_lo[(size_t)brow * 256 + k0 + c8];
    }
    __syncthreads();
    short8 ah[4], al[4];
    #pragma unroll
    for (int mf = 0; mf < 4; ++mf) {
      ah[mf] = *(const short8*)&Ah[(16 * mf + lm) * 40 + 8 * lg];
      al[mf] = *(const short8*)&Al[(16 * mf + lm) * 40 + 8 * lg];
    }
    #pragma unroll
    for (int nf = 0; nf < 4; ++nf) {
      short8 bh = *(const short8*)&Bh[(64 * wv + 16 * nf + lm) * 40 + 8 * lg];
      short8 bl = *(const short8*)&Bl[(64 * wv + 16 * nf + lm) * 40 + 8 * lg];
      #pragma unroll
      for (int mf = 0; mf < 4; ++mf) {
        acc[mf][nf] = __builtin_amdgcn_mfma_f32_16x16x32_bf16(ah[mf], bh, acc[mf][nf], 0, 0, 0);
        acc[mf][nf] = __builtin_amdgcn_mfma_f32_16x16x32_bf16(ah[mf], bl, acc[mf][nf], 0, 0, 0);
        acc[mf][nf] = __builtin_amdgcn_mfma_f32_16x16x32_bf16(al[mf], bh, acc[mf][nf], 0, 0, 0);
      }
    }
  }
  #pragma unroll
  for (int nf = 0; nf < 4; ++nf) {
    int col = 64 * wv + 16 * nf + lm;
    float b = bias[col];
    #pragma unroll
    for (int mf = 0; mf < 4; ++mf) {
      #pragma unroll
      for (int r = 0; r < 4; ++r) {
        int row = m0 + 16 * mf + 4 * lg + r;
        g[(size_t)row * 256 + col] = acc[mf][nf][r] + b;
      }
    }
  }
}

// ---------------- per-node contiguous gather (no atomics) ----------------
__global__ __launch_bounds__(256) void k_gather(
    const ushort* __restrict__ h_hi, const ushort* __restrict__ h_lo,
    const float* __restrict__ g,
    const int* __restrict__ rowstart,
    const int* __restrict__ src_s,
    const float* __restrict__ rn_s,
    const float* __restrict__ v_n,
    const float* __restrict__ icnt,
    int e0, int ce,
    float* __restrict__ hsum, float* __restrict__ v_next)
{
  int t = blockIdx.x;
  int lo = rowstart[t], hi = rowstart[t + 1];
  if (lo < e0) lo = e0;
  int e1 = e0 + ce;
  if (hi > e1) hi = e1;
  if (lo >= hi) return;
  int tid = threadIdx.x;
  int k = tid & 127, half = tid >> 7;
  float hacc = 0.0f, a0 = 0.0f, a1 = 0.0f, a2 = 0.0f;
  for (int p = lo; p < hi; ++p) {
    int lp = p - e0;
    hacc += bf2f(h_hi[(size_t)lp * SD + tid]) + bf2f(h_lo[(size_t)lp * SD + tid]);
    float gr = g[(size_t)lp * SD + k];
    float gv = g[(size_t)lp * SD + 128 + k];
    int sn = src_s[p];
    const float* vs = &v_n[(size_t)sn * 384];
    if (half == 0) {
      float r0 = rn_s[(size_t)p * 4 + 0];
      float r2 = rn_s[(size_t)p * 4 + 2];
      a0 += gr * r0 + gv * vs[k];
      a2 += gr * r2 + gv * vs[256 + k];
    } else {
      float r1 = rn_s[(size_t)p * 4 + 1];
      a1 += gr * r1 + gv * vs[128 + k];
    }
  }
  hsum[(size_t)t * SD + tid] += hacc;
  float ic = icnt[t];
  if (half == 0) {
    v_next[(size_t)t * 384 + k]       += ic * a0;
    v_next[(size_t)t * 384 + 256 + k] += ic * a2;
  } else {
    v_next[(size_t)t * 384 + 128 + k] += ic * a1;
  }
}

// ---------------- nv = sqrt(sum_c vv^2 + eps); xcat = [s | nv] ----------------
__global__ __launch_bounds__(256) void k_nv_xcat(
    const float* __restrict__ vv, const float* __restrict__ s_next,
    float* __restrict__ xcat)
{
  int n = blockIdx.x, t = threadIdx.x;
  xcat[(size_t)n * 384 + t] = s_next[(size_t)n * SD + t];
  if (t < 128) {
    float a = vv[(size_t)(n * 3 + 0) * VD + t];
    float b = vv[(size_t)(n * 3 + 1) * VD + t];
    float c = vv[(size_t)(n * 3 + 2) * VD + t];
    xcat[(size_t)n * 384 + 256 + t] = sqrtf(a * a + b * b + c * c + 1e-6f);
  }
}

// ---------------- s_cur = s_next + u[:, :256]; v_cur = v_next + vv * u[:, None, 256:] ----------------
__global__ __launch_bounds__(256) void k_update(
    const float* __restrict__ s_next, const float* __restrict__ v_next,
    const float* __restrict__ vv, const float* __restrict__ u,
    float* __restrict__ s_cur, float* __restrict__ v_cur)
{
  int i = blockIdx.x * 256 + threadIdx.x;
  const int NVT = NN * 384;
  if (i < NVT) {
    int n = i / 384;
    int k = (i - n * 384) & 127;
    v_cur[i] = v_next[i] + vv[i] * u[(size_t)n * 384 + 256 + k];
  } else {
    int j = i - NVT;
    if (j < NN * SD) {
      int n = j >> 8, c = j & 255;
      s_cur[j] = s_next[j] + u[(size_t)n * 384 + c];
    }
  }
}

// =====================================================================
extern "C" void kernel_launch(void* const* d_in, const int* in_sizes, int n_in,
                              void* d_out, int out_size, void* d_ws, size_t ws_size,
                              hipStream_t stream)
{
  const float* s_in   = (const float*)d_in[0];
  const float* v_in   = (const float*)d_in[1];
  const float* p_in   = (const float*)d_in[2];
  const int*   eidx   = (const int*)d_in[3];
  const float* edge_d = (const float*)d_in[4];
  const float* edge_a = (const float*)d_in[5];
  const float* rnorm  = (const float*)d_in[6];
  const float* edge_e = (const float*)d_in[7];
  const float* edge_o = (const float*)d_in[8];
  const float* edge_g = (const float*)d_in[9];
  const float* gamma  = (const float*)d_in[10];
  const float* beta   = (const float*)d_in[11];
  const float* We1    = (const float*)d_in[12];
  const float* be1    = (const float*)d_in[13];
  const float* We2    = (const float*)d_in[14];
  const float* be2    = (const float*)d_in[15];
  const float* Wvu    = (const float*)d_in[16];
  const float* Wu1    = (const float*)d_in[17];
  const float* bu1    = (const float*)d_in[18];
  const float* Wu2    = (const float*)d_in[19];
  const float* bu2    = (const float*)d_in[20];
  const int* srcA = eidx;
  const int* tgtA = eidx + NE;

  float* w = (float*)d_ws;
  float* s_cur  = w; w += NN * SD;
  float* v_cur  = w; w += NN * 384;
  float* s_ln   = w; w += NN * SD;      // reused later as tbuf
  float* v_nrm  = w; w += NN * 384;     // reused later as ubuf
  float* s_next = w; w += NN * SD;
  float* v_next = w; w += NN * 384;
  float* pre12  = w; w += NN * 512;     // reused later as xcat (N*384)
  float* cnt    = w; w += NN;
  float* icnt   = w; w += NN;
  float* vv     = w; w += NN * 384;     // first NN*256 aliased as hsum
  ushort* wg_hi = (ushort*)w; w += 32768;   // 256*256 bf16
  ushort* wg_lo = (ushort*)w; w += 32768;
  ushort* wt_hi = (ushort*)w; w += 65536;   // up to 512*256 bf16 (node weights)
  ushort* wt_lo = (ushort*)w; w += 65536;
  ushort* w1t_hi = (ushort*)w; w += 12288;  // 256*96 bf16
  ushort* w1t_lo = (ushort*)w; w += 12288;
  ushort* efm_hi = (ushort*)w; w += (size_t)NE * 48;  // NE*96 ushorts
  ushort* efm_lo = (ushort*)w; w += (size_t)NE * 48;
  int*   rowstart = (int*)w; w += NN + 4;   // padded to keep 16B alignment
  int*   fill     = (int*)w; w += NN;
  int*   src_s    = (int*)w; w += NE;
  int*   tgt_s    = (int*)w; w += NE;
  float* rn_s   = w; w += (size_t)NE * 4;
  float* tbuf = s_ln;
  float* ubuf = v_nrm;
  float* xcat = pre12;
  float* hsum = vv;   // lifetimes disjoint: hsum [memset->snext], vv [post-snext->update]

  // chunking: per chunk need chunkE*256 ushort (h_hi) + same (h_lo) + chunkE*256
  // float (g) = chunkE*512 floats total in the remainder
  size_t fixedF = (size_t)(w - (float*)d_ws);
  size_t totalF = ws_size / sizeof(float);
  size_t availF = (totalF > fixedF) ? (totalF - fixedF) : 0;
  long long mc = (long long)(availF / 512) & ~127LL;   // multiple of 128 edges
  if (mc > NE) mc = NE;
  if (mc < 128) mc = 128;
  const int chunkE = (int)mc;
  ushort* h_hi = (ushort*)w;
  ushort* h_lo = h_hi + (size_t)chunkE * SD;
  float*  gbuf = (float*)(h_lo + (size_t)chunkE * SD);
  int*    eperm = (int*)h_hi;   // setup-phase only; dead before first h write

  hipMemsetAsync(cnt, 0, NN * sizeof(float), stream);
  hipMemsetAsync(fill, 0, NN * sizeof(int), stream);
  k_setup<<<(NE + 255) / 256, 256, 0, stream>>>(tgtA, cnt);
  k_scan<<<1, 256, 0, stream>>>(cnt, rowstart);
  k_invcnt<<<(NN + 255) / 256, 256, 0, stream>>>(cnt, icnt);
  k_place<<<(NE + 255) / 256, 256, 0, stream>>>(srcA, tgtA, rnorm, rowstart, fill,
                                                eperm, src_s, tgt_s, rn_s);
  k_efmat<<<NE / 32, 256, 0, stream>>>(edge_d, edge_a, edge_e, edge_o, edge_g,
                                       eperm, efm_hi, efm_lo);

  const int MT = 157;   // ceil(10000/64)
  const float* sp = s_in;
  const float* vp = v_in;
  for (int i = 0; i < 5; ++i) {
    k_ln_vnorm<<<NN, 256, 0, stream>>>(sp, vp, gamma + i * SD, beta + i * SD,
                                       s_ln, s_next, v_nrm, v_next);
    const float* W1 = We1 + (size_t)i * DIN_ * SD;
    const float* W2 = We2 + (size_t)i * SD * 512;
    k_w2bf<<<256, 256, 0, stream>>>(W2, wg_hi, wg_lo);
    k_w1split<<<256, 96, 0, stream>>>(W1 + 512 * SD, w1t_hi, w1t_lo);
    // pre12 = s_ln @ [W1a | W1b]  (combined N=512, K=256) via MFMA
    k_wsplit<<<256, 256, 0, stream>>>(W1, SD, 256, 0, wt_hi, wt_lo);
    k_wsplit<<<256, 256, 0, stream>>>(W1 + 256 * SD, SD, 256, 256, wt_hi, wt_lo);
    k_gemm_mf<0, 0><<<dim3(8, MT), 256, 0, stream>>>(
        s_ln, SD, wt_hi, wt_lo, nullptr, nullptr, nullptr, pre12, 512, NN, 256);
    hipMemsetAsync(hsum, 0, (size_t)NN * SD * sizeof(float), stream);
    for (int e0 = 0; e0 < NE; e0 += chunkE) {
      int ce = NE - e0; if (ce > chunkE) ce = chunkE;
      k_hmf<<<ce / 64, 256, 0, stream>>>(efm_hi, efm_lo, w1t_hi, w1t_lo, pre12,
                                         src_s, tgt_s, be1 + i * SD, e0, h_hi, h_lo);
      k_gmfma<<<ce / 64, 256, 0, stream>>>(h_hi, h_lo, wg_hi, wg_lo,
                                           be2 + i * 512 + 256, gbuf);
      k_gather<<<NN, 256, 0, stream>>>(h_hi, h_lo, gbuf, rowstart, src_s, rn_s,
                                       v_nrm, icnt, e0, ce, hsum, v_next);
    }
    // s_next += (hsum @ We2[:,0:256] + cnt*be2[0:256]) * icnt  via MFMA
    k_wsplit<<<256, 256, 0, stream>>>(W2, 512, 256, 0, wt_hi, wt_lo);
    k_gemm_mf<0, 1><<<dim3(4, MT), 256, 0, stream>>>(
        hsum, SD, wt_hi, wt_lo, be2 + i * 512, cnt, icnt, s_next, SD, NN, 256);
    if (i < 4) {
      k_wsplit<<<128, 256, 0, stream>>>(Wvu + i * VD * VD, VD, VD, 0, wt_hi, wt_lo);
      k_gemm_mf<0, 0><<<dim3(2, 469), 256, 0, stream>>>(
          v_next, VD, wt_hi, wt_lo, nullptr, nullptr, nullptr, vv, VD, 3 * NN, VD);
      k_nv_xcat<<<NN, 256, 0, stream>>>(vv, s_next, xcat);
      k_wsplit<<<256, 256, 0, stream>>>(Wu1 + (size_t)i * 384 * SD, SD, 384, 0, wt_hi, wt_lo);
      k_gemm_mf<1, 0><<<dim3(4, MT), 256, 0, stream>>>(
          xcat, 384, wt_hi, wt_lo, bu1 + i * SD, nullptr, nullptr, tbuf, SD, NN, 384);
      k_wsplit<<<384, 256, 0, stream>>>(Wu2 + (size_t)i * SD * 384, 384, 256, 0, wt_hi, wt_lo);
      k_gemm_mf<0, 0><<<dim3(6, MT), 256, 0, stream>>>(
          tbuf, SD, wt_hi, wt_lo, bu2 + i * 384, nullptr, nullptr, ubuf, 384, NN, 256);
      k_update<<<(NN * 640 + 255) / 256, 256, 0, stream>>>(s_next, v_next, vv, ubuf,
                                                           s_cur, v_cur);
      sp = s_cur; vp = v_cur;
    }
  }
  float* out = (float*)d_out;
  k_ln_vnorm<<<NN, 256, 0, stream>>>(s_next, v_next, gamma + 5 * SD, beta + 5 * SD,
                                     out, nullptr, out + NN * SD, nullptr);
  float* outp = out + (size_t)NN * SD + (size_t)NN * 384;
  hipMemcpyAsync(outp, p_in, NN * 3 * sizeof(float), hipMemcpyDeviceToDevice, stream);
  hipMemcpyAsync(outp + NN * 3, edge_e, (size_t)NE * 32 * sizeof(float),
                 hipMemcpyDeviceToDevice, stream);
}